// Round 4
// baseline (1013.660 us; speedup 1.0000x reference)
//
#include <hip/hip_runtime.h>
#include <stdint.h>

#define B_ 32
#define S_ 128
#define T_ 128
#define V_ 32000
#define E_ 256
#define H_ 256
#define NEG_ (-1.0e9f)

typedef __attribute__((ext_vector_type(8))) short short8;
typedef __attribute__((ext_vector_type(4))) float floatx4;

__device__ __forceinline__ unsigned short f2bf(float x){
  unsigned u = __float_as_uint(x);
  u = u + 0x7fffu + ((u >> 16) & 1u);   // RNE
  return (unsigned short)(u >> 16);
}
__device__ __forceinline__ float bf2f(unsigned short s){
  return __uint_as_float(((unsigned)s) << 16);
}
__device__ __forceinline__ float hsum4(float4 v){ return (v.x+v.y)+(v.z+v.w); }
__device__ __forceinline__ void unpack8(uint4 q, float4& lo, float4& hi){
  lo.x = __uint_as_float(q.x << 16); lo.y = __uint_as_float(q.x & 0xffff0000u);
  lo.z = __uint_as_float(q.y << 16); lo.w = __uint_as_float(q.y & 0xffff0000u);
  hi.x = __uint_as_float(q.z << 16); hi.y = __uint_as_float(q.z & 0xffff0000u);
  hi.z = __uint_as_float(q.w << 16); hi.w = __uint_as_float(q.w & 0xffff0000u);
}

// async global->LDS, 16B per lane (wave-uniform LDS base + lane*16 rule)
#define GLOAD_LDS16(gptr, lptr) \
  __builtin_amdgcn_global_load_lds( \
      (const __attribute__((address_space(1))) unsigned int*)(const void*)(gptr), \
      (__attribute__((address_space(3))) unsigned int*)(void*)(lptr), 16, 0, 0)

// LDS-visibility barrier WITHOUT vmcnt drain: global stores stay in flight.
#define LDS_BARRIER() do { \
    asm volatile("s_waitcnt lgkmcnt(0)" ::: "memory"); \
    __builtin_amdgcn_s_barrier(); \
  } while(0)

// ================= fused prep: cvt(W_out), cvt(W_attn), xih_enc, xih_dec =====
__device__ __forceinline__ void cvt_body(const float* __restrict__ src,
                                         unsigned short* __restrict__ dst,
                                         int blk, int n4){
  int i = blk*256 + (int)threadIdx.x;
  if (i < n4){
    float4 v = ((const float4*)src)[i];
    ushort4 o; o.x=f2bf(v.x); o.y=f2bf(v.y); o.z=f2bf(v.z); o.w=f2bf(v.w);
    ((ushort4*)dst)[i] = o;
  }
}

__device__ __forceinline__ void xih_body(
    const int* __restrict__ idxmat, const float* __restrict__ emb,
    const float* __restrict__ Wih,
    const float* __restrict__ b1, const float* __restrict__ b2,
    float* __restrict__ out, int blk,
    int* idx_s, float4 (*x_s)[64])
{
  int b = blk >> 3;
  int t0 = (blk & 7) << 4;
  int tid = threadIdx.x;
  if (tid < 16) idx_s[tid] = idxmat[b*128 + t0 + tid];
  __syncthreads();
  for (int r = 0; r < 16; ++r)
    ((float*)&x_s[r][0])[tid] = emb[(size_t)idx_s[r]*E_ + tid];
  __syncthreads();
  int j2 = tid & 127, tg = tid >> 7;
  const float4* W0 = (const float4*)(Wih + (size_t)j2*E_);
  const float4* W1 = (const float4*)(Wih + (size_t)(j2+128)*E_);
  float4 a0[8], a1[8];
  #pragma unroll
  for (int t=0;t<8;++t){ a0[t]={0,0,0,0}; a1[t]={0,0,0,0}; }
  for (int e4 = 0; e4 < 64; ++e4){
    float4 w0 = W0[e4], w1 = W1[e4];
    #pragma unroll
    for (int t = 0; t < 8; ++t){
      float4 xv = x_s[tg*8+t][e4];               // LDS broadcast
      a0[t] += w0*xv; a1[t] += w1*xv;
    }
  }
  float bi0 = b1[j2] + b2[j2];
  float bi1 = b1[j2+128] + b2[j2+128];
  #pragma unroll
  for (int t = 0; t < 8; ++t){
    size_t row = (size_t)((b<<7) + t0 + tg*8 + t)*H_;
    out[row + j2]     = hsum4(a0[t]) + bi0;
    out[row + j2+128] = hsum4(a1[t]) + bi1;
  }
}

// grid: 8000 (cvt Wout) + 128 (cvt Wattn) + 256 (xih enc) + 256 (xih dec) = 8640
__global__ __launch_bounds__(256) void k_prep(
    const float* __restrict__ W_out, unsigned short* __restrict__ Wout_bf,
    const float* __restrict__ W_attn, unsigned short* __restrict__ Wattn_bf,
    const int* __restrict__ indices_de, const float* __restrict__ emb_enc,
    const float* __restrict__ W_ih_enc, const float* __restrict__ b_ih_enc,
    const float* __restrict__ b_hh_enc, float* __restrict__ Xih_enc,
    const int* __restrict__ indices_en, const float* __restrict__ emb_dec,
    const float* __restrict__ W_ih_dec, const float* __restrict__ b_ih_dec,
    const float* __restrict__ b_hh_dec, float* __restrict__ Xih_dec)
{
  __shared__ int idx_s[16];
  __shared__ float4 x_s[16][64];
  int bx = blockIdx.x;
  if (bx < 8000){
    cvt_body(W_out, Wout_bf, bx, 2048000);
  } else if (bx < 8128){
    cvt_body(W_attn, Wattn_bf, bx - 8000, 32768);
  } else if (bx < 8384){
    xih_body(indices_de, emb_enc, W_ih_enc, b_ih_enc, b_hh_enc, Xih_enc,
             bx - 8128, idx_s, x_s);
  } else {
    xih_body(indices_en, emb_dec, W_ih_dec, b_ih_dec, b_hh_dec, Xih_dec,
             bx - 8384, idx_s, x_s);
  }
}

// ============ fused enc+dec RNN recurrence, one block per batch row ==========
__global__ __launch_bounds__(512, 2) void k_rnn2(
    const float* __restrict__ Whh_e, const float* __restrict__ Whh_d,
    const float* __restrict__ Xih_e, const float* __restrict__ Xih_d,
    const int* __restrict__ lengths,
    unsigned short* __restrict__ enc_out,  // bf16 [B][S][H]
    float* __restrict__ hseq)              // f32 [B][T][H]
{
  __shared__ float h_s[256];
  __shared__ float part[8][256];
  int b = blockIdx.x, tid = threadIdx.x;
  int kk = tid >> 6;          // 0..7, uniform within a wave
  int jg = tid & 63;
  float4 w[4][8];             // 128 VGPRs of W
  #pragma unroll
  for (int r = 0; r < 4; ++r){
    const float4* Wr = (const float4*)(Whh_e + (size_t)(jg + (r<<6))*H_ + (kk<<5));
    #pragma unroll
    for (int i = 0; i < 8; ++i) w[r][i] = Wr[i];
  }
  if (tid < 256) h_s[tid] = 0.f;
  int len = lengths[b];
  __syncthreads();

  // ---- encoder: 128 steps, h frozen past length ----
  for (int t = 0; t < 128; ++t){
    float x = 0.f;
    if (tid < 256) x = Xih_e[(size_t)((b<<7) + t)*H_ + tid];  // early issue
    const float4* h4 = ((const float4*)h_s) + (kk << 3);
    float4 hv[8];
    #pragma unroll
    for (int i = 0; i < 8; ++i) hv[i] = h4[i];     // broadcast reads
    #pragma unroll
    for (int r = 0; r < 4; ++r){
      float4 a = {0,0,0,0};
      #pragma unroll
      for (int i = 0; i < 8; ++i) a += w[r][i]*hv[i];
      part[kk][jg + (r<<6)] = hsum4(a);
    }
    LDS_BARRIER();
    if (tid < 256){
      float s = x;
      #pragma unroll
      for (int q = 0; q < 8; ++q) s += part[q][tid];
      float hn = tanhf(s);
      float hold = h_s[tid];
      bool v = (t < len);
      h_s[tid] = v ? hn : hold;
      enc_out[(size_t)((b<<7)+t)*H_ + tid] = f2bf(v ? hn : 0.f);
    }
    LDS_BARRIER();
  }

  // ---- decoder: reload W, h0 = enc final h already in LDS ----
  #pragma unroll
  for (int r = 0; r < 4; ++r){
    const float4* Wr = (const float4*)(Whh_d + (size_t)(jg + (r<<6))*H_ + (kk<<5));
    #pragma unroll
    for (int i = 0; i < 8; ++i) w[r][i] = Wr[i];
  }
  for (int t = 0; t < 128; ++t){
    float x = 0.f;
    if (tid < 256) x = Xih_d[(size_t)((b<<7) + t)*H_ + tid];
    const float4* h4 = ((const float4*)h_s) + (kk << 3);
    float4 hv[8];
    #pragma unroll
    for (int i = 0; i < 8; ++i) hv[i] = h4[i];
    #pragma unroll
    for (int r = 0; r < 4; ++r){
      float4 a = {0,0,0,0};
      #pragma unroll
      for (int i = 0; i < 8; ++i) a += w[r][i]*hv[i];
      part[kk][jg + (r<<6)] = hsum4(a);
    }
    LDS_BARRIER();
    if (tid < 256){
      float s = x;
      #pragma unroll
      for (int q = 0; q < 8; ++q) s += part[q][tid];
      float hn = tanhf(s);
      h_s[tid] = hn;
      hseq[(size_t)((b<<7)+t)*H_ + tid] = hn;
    }
    LDS_BARRIER();
  }
}

// ---------------- attention + combine (parallel over b, t-tiles of 16) --------
__global__ __launch_bounds__(256) void k_attn(
    const unsigned short* __restrict__ enc_out, // bf16 [B][S][H]
    const float* __restrict__ hseq,             // [B][T][H]
    const int* __restrict__ lengths,
    const unsigned short* __restrict__ Wattn,   // bf16 [H][2H]
    const float* __restrict__ battn,            // [H]
    unsigned short* __restrict__ attn_out)      // bf16 [B*T][H]
{
  __shared__ float h_sm[16][256];   // 16 KB
  __shared__ float sc[16][132];     // 8.25 KB (pad 4)
  __shared__ float comb[16][512];   // 32 KB : [context | h]
  int bx = blockIdx.x; int b = bx >> 3; int t0 = (bx & 7) << 4;
  int tid = threadIdx.x;
  int len = lengths[b];
  for (int r = 0; r < 16; ++r)
    h_sm[r][tid] = hseq[(size_t)((b<<7) + t0 + r)*H_ + tid];
  __syncthreads();
  // phase 1: scores[t][s] = h_t . enc_s
  {
    int s = tid & 127, tg = tid >> 7;
    float4 a[8];
    #pragma unroll
    for (int t=0;t<8;++t) a[t] = {0,0,0,0};
    const uint4* ep = (const uint4*)(enc_out + (size_t)(b*S_ + s)*H_);
    for (int oct = 0; oct < 32; ++oct){
      uint4 q = ep[oct];
      float4 elo, ehi; unpack8(q, elo, ehi);
      #pragma unroll
      for (int t = 0; t < 8; ++t){
        const float4* hp = (const float4*)&h_sm[tg*8+t][oct*8]; // broadcast
        a[t] += elo*hp[0] + ehi*hp[1];
      }
    }
    #pragma unroll
    for (int t = 0; t < 8; ++t)
      sc[tg*8+t][s] = (s < len) ? hsum4(a[t]) : NEG_;
  }
  __syncthreads();
  // phase 2: softmax per row
  {
    int wv = tid >> 6, ln = tid & 63;
    for (int r = 0; r < 4; ++r){
      int t = r*4 + wv;
      float v0 = sc[t][ln], v1 = sc[t][ln+64];
      float m = fmaxf(v0, v1);
      #pragma unroll
      for (int off = 32; off >= 1; off >>= 1) m = fmaxf(m, __shfl_xor(m, off));
      float e0 = __expf(v0 - m), e1 = __expf(v1 - m);
      float su = e0 + e1;
      #pragma unroll
      for (int off = 32; off >= 1; off >>= 1) su += __shfl_xor(su, off);
      float inv = 1.0f / su;
      sc[t][ln] = e0*inv; sc[t][ln+64] = e1*inv;
    }
  }
  __syncthreads();
  // phase 3: context
  {
    int hd = tid & 127, tg = tid >> 7;
    float c0[8], c1[8];
    #pragma unroll
    for (int t=0;t<8;++t){ c0[t]=0.f; c1[t]=0.f; }
    for (int s4 = 0; s4 < 32; ++s4){
      float ea[4], eb[4];
      #pragma unroll
      for (int i = 0; i < 4; ++i){
        const unsigned short* er = enc_out + (size_t)(b*S_ + s4*4 + i)*H_;
        ea[i] = bf2f(er[hd]); eb[i] = bf2f(er[hd+128]);
      }
      #pragma unroll
      for (int t = 0; t < 8; ++t){
        float4 av = *(const float4*)&sc[tg*8+t][s4*4];   // broadcast
        c0[t] += av.x*ea[0] + av.y*ea[1] + av.z*ea[2] + av.w*ea[3];
        c1[t] += av.x*eb[0] + av.y*eb[1] + av.z*eb[2] + av.w*eb[3];
      }
    }
    #pragma unroll
    for (int t = 0; t < 8; ++t){
      comb[tg*8+t][hd]     = c0[t];
      comb[tg*8+t][hd+128] = c1[t];
    }
  }
  for (int r = 0; r < 16; ++r) comb[r][256 + tid] = h_sm[r][tid];
  __syncthreads();
  // phase 4: attn_out = tanh(W_attn . comb + b)
  {
    int j2 = tid & 127, tg = tid >> 7;
    float4 a0[8], a1[8];
    #pragma unroll
    for (int t=0;t<8;++t){ a0[t]={0,0,0,0}; a1[t]={0,0,0,0}; }
    const uint4* W0 = (const uint4*)(Wattn + (size_t)j2*512);
    const uint4* W1 = (const uint4*)(Wattn + (size_t)(j2+128)*512);
    for (int oct = 0; oct < 64; ++oct){
      float4 w0lo, w0hi, w1lo, w1hi;
      unpack8(W0[oct], w0lo, w0hi);
      unpack8(W1[oct], w1lo, w1hi);
      #pragma unroll
      for (int t = 0; t < 8; ++t){
        const float4* cp = (const float4*)&comb[tg*8+t][oct*8]; // broadcast
        float4 clo = cp[0], chi = cp[1];
        a0[t] += w0lo*clo + w0hi*chi;
        a1[t] += w1lo*clo + w1hi*chi;
      }
    }
    float bi0 = battn[j2], bi1 = battn[j2+128];
    #pragma unroll
    for (int t = 0; t < 8; ++t){
      size_t row = (size_t)((b<<7) + t0 + tg*8 + t)*H_;
      attn_out[row + j2]     = f2bf(tanhf(hsum4(a0[t]) + bi0));
      attn_out[row + j2+128] = f2bf(tanhf(hsum4(a1[t]) + bi1));
    }
  }
}

// ---------------- vocab projection: [4096,256]bf16 @ W_out^T -> fp32 ----------
// WAVE-PRIVATE staging, ZERO barriers in the K-loop. Block = 256x64 output,
// 4 waves x (64x64). Each wave stages its own A(64x32) and B(64x32) k-tiles
// into private double-buffered LDS (64 KB/block -> 2 blocks/CU). Since a wave
// only reads LDS it wrote itself, per-wave vmcnt(8) proves arrival (no cross-
// wave barrier needed). WAR on buffer reuse guarded by lgkmcnt(0) before the
// re-stage. XCD-chunked mapping: each XCD gets a contiguous 1000-block run so
// B panels stay L2-resident per XCD.
__global__ __launch_bounds__(256) void k_vocab(
    const unsigned short* __restrict__ A,   // attn_out bf16 [4096][256]
    const unsigned short* __restrict__ Wb,  // W_out bf16 [V][256]
    const float* __restrict__ bout,         // [V]
    float* __restrict__ out)                // [4096][V]
{
  __shared__ alignas(16) unsigned short Aw[4][2][64*32];  // 32 KB
  __shared__ alignas(16) unsigned short Bw[4][2][64*32];  // 32 KB
  int bid = blockIdx.x;                  // 8000 blocks
  int xcd = bid & 7;
  int gid = xcd*1000 + (bid >> 3);       // bijective chunked (8000 % 8 == 0)
  int mb = gid & 15, nb = gid >> 4;      // consecutive gid share nb-panel
  int tid = threadIdx.x;
  int ln  = tid & 63;
  int w   = tid >> 6;                    // wave id 0..3
  int llo = ln & 15, lhi = ln >> 4;
  int mbase = mb*256 + w*64, nbase = nb*64;

  // staging geometry: per tile, per wave: A = 4 instr x (64 lanes x 16B),
  // B same. instr i covers rows i*16 + (ln>>2); per-lane k-slot is constant:
  // slot = (ln&3) ^ ((ln>>3)&3)  [XOR swizzle, rows mult of 16 in i]
  int rowb = ln >> 2;
  int slot = (ln & 3) ^ ((ln >> 3) & 3);
  const unsigned short* Ag = A  + (size_t)(mbase + rowb)*256 + slot*8;
  const unsigned short* Bg = Wb + (size_t)(nbase + rowb)*256 + slot*8;
  unsigned short* AwB = &Aw[w][0][0];    // wave-uniform LDS bases
  unsigned short* BwB = &Bw[w][0][0];

#define STAGE_T(bufi, kt) do { \
    const unsigned short* As_ = Ag + (kt)*32; \
    const unsigned short* Bs_ = Bg + (kt)*32; \
    unsigned short* Ad_ = AwB + (bufi)*2048; \
    unsigned short* Bd_ = BwB + (bufi)*2048; \
    GLOAD_LDS16(As_ +     0, Ad_ +    0); \
    GLOAD_LDS16(As_ +  4096, Ad_ +  512); \
    GLOAD_LDS16(As_ +  8192, Ad_ + 1024); \
    GLOAD_LDS16(As_ + 12288, Ad_ + 1536); \
    GLOAD_LDS16(Bs_ +     0, Bd_ +    0); \
    GLOAD_LDS16(Bs_ +  4096, Bd_ +  512); \
    GLOAD_LDS16(Bs_ +  8192, Bd_ + 1024); \
    GLOAD_LDS16(Bs_ + 12288, Bd_ + 1536); \
  } while(0)

  floatx4 acc[4][4];
  #pragma unroll
  for (int mi=0;mi<4;++mi)
    #pragma unroll
    for (int ni=0;ni<4;++ni) acc[mi][ni] = (floatx4){0.f,0.f,0.f,0.f};

  // swizzled read offsets (shorts) within the wave's 64x32 tile
  int q = (llo >> 1) & 3;
  int aoff[4];
  #pragma unroll
  for (int i=0;i<4;++i) aoff[i] = (i*16 + llo)*32 + ((lhi ^ q)*8);

  STAGE_T(0, 0);
  STAGE_T(1, 1);                          // 16 loads outstanding

  #pragma unroll
  for (int k0 = 0; k0 < 8; ++k0){
    // tile k0's 8 loads arrived; next tile's 8 may remain in flight
    if (k0 < 7) asm volatile("s_waitcnt vmcnt(8)" ::: "memory");
    else        asm volatile("s_waitcnt vmcnt(0)" ::: "memory");
    int buf = k0 & 1;
    const unsigned short* Ar = AwB + buf*2048;
    const unsigned short* Br = BwB + buf*2048;
    short8 afr[4], bfr[4];
    #pragma unroll
    for (int mi=0;mi<4;++mi) afr[mi] = *(const short8*)(Ar + aoff[mi]);
    #pragma unroll
    for (int ni=0;ni<4;++ni) bfr[ni] = *(const short8*)(Br + aoff[ni]);
    // my reads of this buffer are done -> safe to overwrite it with tile k0+2
    asm volatile("s_waitcnt lgkmcnt(0)" ::: "memory");
    if (k0 < 6) STAGE_T(buf, k0+2);
    #pragma unroll
    for (int ni=0;ni<4;++ni)
      #pragma unroll
      for (int mi=0;mi<4;++mi)
        acc[mi][ni] = __builtin_amdgcn_mfma_f32_16x16x32_bf16(afr[mi], bfr[ni], acc[mi][ni], 0, 0, 0);
  }

  // epilogue: C/D layout col=lane&15, row=(lane>>4)*4+r
  #pragma unroll
  for (int ni = 0; ni < 4; ++ni){
    int col = nbase + ni*16 + llo;
    float bias = bout[col];
    #pragma unroll
    for (int mi = 0; mi < 4; ++mi){
      #pragma unroll
      for (int r = 0; r < 4; ++r){
        int row = mbase + mi*16 + lhi*4 + r;
        out[(size_t)row*V_ + col] = acc[mi][ni][r] + bias;
      }
    }
  }
#undef STAGE_T
}

extern "C" void kernel_launch(void* const* d_in, const int* in_sizes, int n_in,
                              void* d_out, int out_size, void* d_ws, size_t ws_size,
                              hipStream_t stream){
  const int*   indices_de = (const int*)d_in[0];
  const int*   lengths_de = (const int*)d_in[1];
  const int*   indices_en = (const int*)d_in[2];
  const float* emb_enc   = (const float*)d_in[4];
  const float* emb_dec   = (const float*)d_in[5];
  const float* W_ih_enc  = (const float*)d_in[6];
  const float* W_hh_enc  = (const float*)d_in[7];
  const float* b_ih_enc  = (const float*)d_in[8];
  const float* b_hh_enc  = (const float*)d_in[9];
  const float* W_ih_dec  = (const float*)d_in[10];
  const float* W_hh_dec  = (const float*)d_in[11];
  const float* b_ih_dec  = (const float*)d_in[12];
  const float* b_hh_dec  = (const float*)d_in[13];
  const float* W_attn    = (const float*)d_in[14];
  const float* b_attn    = (const float*)d_in[15];
  const float* W_out     = (const float*)d_in[16];
  const float* b_out     = (const float*)d_in[17];

  char* ws = (char*)d_ws;
  size_t o = 0;
  float* Xih_enc = (float*)(ws + o); o += (size_t)4096*256*4;
  float* Xih_dec = (float*)(ws + o); o += (size_t)4096*256*4;
  unsigned short* enc_bf = (unsigned short*)(ws + o); o += (size_t)4096*256*2;
  float* hdec    = (float*)(ws + o); o += (size_t)4096*256*4;
  unsigned short* attn_o  = (unsigned short*)(ws + o); o += (size_t)4096*256*2;
  unsigned short* Wout_bf = (unsigned short*)(ws + o); o += (size_t)V_*256*2;
  unsigned short* Wattn_bf= (unsigned short*)(ws + o); o += (size_t)256*512*2;

  k_prep<<<8640, 256, 0, stream>>>(
      W_out, Wout_bf, W_attn, Wattn_bf,
      indices_de, emb_enc, W_ih_enc, b_ih_enc, b_hh_enc, Xih_enc,
      indices_en, emb_dec, W_ih_dec, b_ih_dec, b_hh_dec, Xih_dec);
  k_rnn2<<<32, 512, 0, stream>>>(W_hh_enc, W_hh_dec, Xih_enc, Xih_dec,
                                 lengths_de, enc_bf, hdec);
  k_attn<<<256, 256, 0, stream>>>(enc_bf, hdec, lengths_de, Wattn_bf, b_attn, attn_o);
  k_vocab<<<8000, 256, 0, stream>>>(attn_o, Wout_bf, b_out, (float*)d_out);
}

// Round 5
// 943.877 us; speedup vs baseline: 1.0739x; 1.0739x over previous
//
#include <hip/hip_runtime.h>
#include <stdint.h>

#define B_ 32
#define S_ 128
#define T_ 128
#define V_ 32000
#define E_ 256
#define H_ 256
#define NEG_ (-1.0e9f)

typedef __attribute__((ext_vector_type(8))) short short8;
typedef __attribute__((ext_vector_type(4))) float floatx4;

__device__ __forceinline__ unsigned short f2bf(float x){
  unsigned u = __float_as_uint(x);
  u = u + 0x7fffu + ((u >> 16) & 1u);   // RNE
  return (unsigned short)(u >> 16);
}
__device__ __forceinline__ float bf2f(unsigned short s){
  return __uint_as_float(((unsigned)s) << 16);
}
__device__ __forceinline__ float hsum4(float4 v){ return (v.x+v.y)+(v.z+v.w); }
__device__ __forceinline__ void unpack8(uint4 q, float4& lo, float4& hi){
  lo.x = __uint_as_float(q.x << 16); lo.y = __uint_as_float(q.x & 0xffff0000u);
  lo.z = __uint_as_float(q.y << 16); lo.w = __uint_as_float(q.y & 0xffff0000u);
  hi.x = __uint_as_float(q.z << 16); hi.y = __uint_as_float(q.z & 0xffff0000u);
  hi.z = __uint_as_float(q.w << 16); hi.w = __uint_as_float(q.w & 0xffff0000u);
}

// async global->LDS, 16B per lane (wave-uniform LDS base + lane*16 rule)
#define GLOAD_LDS16(gptr, lptr) \
  __builtin_amdgcn_global_load_lds( \
      (const __attribute__((address_space(1))) unsigned int*)(const void*)(gptr), \
      (__attribute__((address_space(3))) unsigned int*)(void*)(lptr), 16, 0, 0)

// LDS-visibility barrier WITHOUT vmcnt drain: global stores stay in flight.
#define LDS_BARRIER() do { \
    asm volatile("s_waitcnt lgkmcnt(0)" ::: "memory"); \
    __builtin_amdgcn_s_barrier(); \
  } while(0)

// ================= fused prep: cvt(W_out), cvt(W_attn), xih_enc, xih_dec =====
__device__ __forceinline__ void cvt_body(const float* __restrict__ src,
                                         unsigned short* __restrict__ dst,
                                         int blk, int n4){
  int i = blk*256 + (int)threadIdx.x;
  if (i < n4){
    float4 v = ((const float4*)src)[i];
    ushort4 o; o.x=f2bf(v.x); o.y=f2bf(v.y); o.z=f2bf(v.z); o.w=f2bf(v.w);
    ((ushort4*)dst)[i] = o;
  }
}

__device__ __forceinline__ void xih_body(
    const int* __restrict__ idxmat, const float* __restrict__ emb,
    const float* __restrict__ Wih,
    const float* __restrict__ b1, const float* __restrict__ b2,
    float* __restrict__ out, int blk,
    int* idx_s, float4 (*x_s)[64])
{
  int b = blk >> 3;
  int t0 = (blk & 7) << 4;
  int tid = threadIdx.x;
  if (tid < 16) idx_s[tid] = idxmat[b*128 + t0 + tid];
  __syncthreads();
  for (int r = 0; r < 16; ++r)
    ((float*)&x_s[r][0])[tid] = emb[(size_t)idx_s[r]*E_ + tid];
  __syncthreads();
  int j2 = tid & 127, tg = tid >> 7;
  const float4* W0 = (const float4*)(Wih + (size_t)j2*E_);
  const float4* W1 = (const float4*)(Wih + (size_t)(j2+128)*E_);
  float4 a0[8], a1[8];
  #pragma unroll
  for (int t=0;t<8;++t){ a0[t]={0,0,0,0}; a1[t]={0,0,0,0}; }
  for (int e4 = 0; e4 < 64; ++e4){
    float4 w0 = W0[e4], w1 = W1[e4];
    #pragma unroll
    for (int t = 0; t < 8; ++t){
      float4 xv = x_s[tg*8+t][e4];               // LDS broadcast
      a0[t] += w0*xv; a1[t] += w1*xv;
    }
  }
  float bi0 = b1[j2] + b2[j2];
  float bi1 = b1[j2+128] + b2[j2+128];
  #pragma unroll
  for (int t = 0; t < 8; ++t){
    size_t row = (size_t)((b<<7) + t0 + tg*8 + t)*H_;
    out[row + j2]     = hsum4(a0[t]) + bi0;
    out[row + j2+128] = hsum4(a1[t]) + bi1;
  }
}

// grid: 8000 (cvt Wout) + 128 (cvt Wattn) + 256 (xih enc) + 256 (xih dec) = 8640
__global__ __launch_bounds__(256) void k_prep(
    const float* __restrict__ W_out, unsigned short* __restrict__ Wout_bf,
    const float* __restrict__ W_attn, unsigned short* __restrict__ Wattn_bf,
    const int* __restrict__ indices_de, const float* __restrict__ emb_enc,
    const float* __restrict__ W_ih_enc, const float* __restrict__ b_ih_enc,
    const float* __restrict__ b_hh_enc, float* __restrict__ Xih_enc,
    const int* __restrict__ indices_en, const float* __restrict__ emb_dec,
    const float* __restrict__ W_ih_dec, const float* __restrict__ b_ih_dec,
    const float* __restrict__ b_hh_dec, float* __restrict__ Xih_dec)
{
  __shared__ int idx_s[16];
  __shared__ float4 x_s[16][64];
  int bx = blockIdx.x;
  if (bx < 8000){
    cvt_body(W_out, Wout_bf, bx, 2048000);
  } else if (bx < 8128){
    cvt_body(W_attn, Wattn_bf, bx - 8000, 32768);
  } else if (bx < 8384){
    xih_body(indices_de, emb_enc, W_ih_enc, b_ih_enc, b_hh_enc, Xih_enc,
             bx - 8128, idx_s, x_s);
  } else {
    xih_body(indices_en, emb_dec, W_ih_dec, b_ih_dec, b_hh_dec, Xih_dec,
             bx - 8384, idx_s, x_s);
  }
}

// ============ fused enc+dec RNN recurrence, one block per batch row ==========
__global__ __launch_bounds__(512, 2) void k_rnn2(
    const float* __restrict__ Whh_e, const float* __restrict__ Whh_d,
    const float* __restrict__ Xih_e, const float* __restrict__ Xih_d,
    const int* __restrict__ lengths,
    unsigned short* __restrict__ enc_out,  // bf16 [B][S][H]
    float* __restrict__ hseq)              // f32 [B][T][H]
{
  __shared__ float h_s[256];
  __shared__ float part[8][256];
  int b = blockIdx.x, tid = threadIdx.x;
  int kk = tid >> 6;          // 0..7, uniform within a wave
  int jg = tid & 63;
  float4 w[4][8];             // 128 VGPRs of W
  #pragma unroll
  for (int r = 0; r < 4; ++r){
    const float4* Wr = (const float4*)(Whh_e + (size_t)(jg + (r<<6))*H_ + (kk<<5));
    #pragma unroll
    for (int i = 0; i < 8; ++i) w[r][i] = Wr[i];
  }
  if (tid < 256) h_s[tid] = 0.f;
  int len = lengths[b];
  __syncthreads();

  // ---- encoder: 128 steps, h frozen past length ----
  for (int t = 0; t < 128; ++t){
    float x = 0.f;
    if (tid < 256) x = Xih_e[(size_t)((b<<7) + t)*H_ + tid];  // early issue
    const float4* h4 = ((const float4*)h_s) + (kk << 3);
    float4 hv[8];
    #pragma unroll
    for (int i = 0; i < 8; ++i) hv[i] = h4[i];     // broadcast reads
    #pragma unroll
    for (int r = 0; r < 4; ++r){
      float4 a = {0,0,0,0};
      #pragma unroll
      for (int i = 0; i < 8; ++i) a += w[r][i]*hv[i];
      part[kk][jg + (r<<6)] = hsum4(a);
    }
    LDS_BARRIER();
    if (tid < 256){
      float s = x;
      #pragma unroll
      for (int q = 0; q < 8; ++q) s += part[q][tid];
      float hn = tanhf(s);
      float hold = h_s[tid];
      bool v = (t < len);
      h_s[tid] = v ? hn : hold;
      enc_out[(size_t)((b<<7)+t)*H_ + tid] = f2bf(v ? hn : 0.f);
    }
    LDS_BARRIER();
  }

  // ---- decoder: reload W, h0 = enc final h already in LDS ----
  #pragma unroll
  for (int r = 0; r < 4; ++r){
    const float4* Wr = (const float4*)(Whh_d + (size_t)(jg + (r<<6))*H_ + (kk<<5));
    #pragma unroll
    for (int i = 0; i < 8; ++i) w[r][i] = Wr[i];
  }
  for (int t = 0; t < 128; ++t){
    float x = 0.f;
    if (tid < 256) x = Xih_d[(size_t)((b<<7) + t)*H_ + tid];
    const float4* h4 = ((const float4*)h_s) + (kk << 3);
    float4 hv[8];
    #pragma unroll
    for (int i = 0; i < 8; ++i) hv[i] = h4[i];
    #pragma unroll
    for (int r = 0; r < 4; ++r){
      float4 a = {0,0,0,0};
      #pragma unroll
      for (int i = 0; i < 8; ++i) a += w[r][i]*hv[i];
      part[kk][jg + (r<<6)] = hsum4(a);
    }
    LDS_BARRIER();
    if (tid < 256){
      float s = x;
      #pragma unroll
      for (int q = 0; q < 8; ++q) s += part[q][tid];
      float hn = tanhf(s);
      h_s[tid] = hn;
      hseq[(size_t)((b<<7)+t)*H_ + tid] = hn;
    }
    LDS_BARRIER();
  }
}

// ---------------- attention + combine (parallel over b, t-tiles of 16) --------
__global__ __launch_bounds__(256) void k_attn(
    const unsigned short* __restrict__ enc_out, // bf16 [B][S][H]
    const float* __restrict__ hseq,             // [B][T][H]
    const int* __restrict__ lengths,
    const unsigned short* __restrict__ Wattn,   // bf16 [H][2H]
    const float* __restrict__ battn,            // [H]
    unsigned short* __restrict__ attn_out)      // bf16 [B*T][H]
{
  __shared__ float h_sm[16][256];   // 16 KB
  __shared__ float sc[16][132];     // 8.25 KB (pad 4)
  __shared__ float comb[16][512];   // 32 KB : [context | h]
  int bx = blockIdx.x; int b = bx >> 3; int t0 = (bx & 7) << 4;
  int tid = threadIdx.x;
  int len = lengths[b];
  for (int r = 0; r < 16; ++r)
    h_sm[r][tid] = hseq[(size_t)((b<<7) + t0 + r)*H_ + tid];
  __syncthreads();
  // phase 1: scores[t][s] = h_t . enc_s
  {
    int s = tid & 127, tg = tid >> 7;
    float4 a[8];
    #pragma unroll
    for (int t=0;t<8;++t) a[t] = {0,0,0,0};
    const uint4* ep = (const uint4*)(enc_out + (size_t)(b*S_ + s)*H_);
    for (int oct = 0; oct < 32; ++oct){
      uint4 q = ep[oct];
      float4 elo, ehi; unpack8(q, elo, ehi);
      #pragma unroll
      for (int t = 0; t < 8; ++t){
        const float4* hp = (const float4*)&h_sm[tg*8+t][oct*8]; // broadcast
        a[t] += elo*hp[0] + ehi*hp[1];
      }
    }
    #pragma unroll
    for (int t = 0; t < 8; ++t)
      sc[tg*8+t][s] = (s < len) ? hsum4(a[t]) : NEG_;
  }
  __syncthreads();
  // phase 2: softmax per row
  {
    int wv = tid >> 6, ln = tid & 63;
    for (int r = 0; r < 4; ++r){
      int t = r*4 + wv;
      float v0 = sc[t][ln], v1 = sc[t][ln+64];
      float m = fmaxf(v0, v1);
      #pragma unroll
      for (int off = 32; off >= 1; off >>= 1) m = fmaxf(m, __shfl_xor(m, off));
      float e0 = __expf(v0 - m), e1 = __expf(v1 - m);
      float su = e0 + e1;
      #pragma unroll
      for (int off = 32; off >= 1; off >>= 1) su += __shfl_xor(su, off);
      float inv = 1.0f / su;
      sc[t][ln] = e0*inv; sc[t][ln+64] = e1*inv;
    }
  }
  __syncthreads();
  // phase 3: context
  {
    int hd = tid & 127, tg = tid >> 7;
    float c0[8], c1[8];
    #pragma unroll
    for (int t=0;t<8;++t){ c0[t]=0.f; c1[t]=0.f; }
    for (int s4 = 0; s4 < 32; ++s4){
      float ea[4], eb[4];
      #pragma unroll
      for (int i = 0; i < 4; ++i){
        const unsigned short* er = enc_out + (size_t)(b*S_ + s4*4 + i)*H_;
        ea[i] = bf2f(er[hd]); eb[i] = bf2f(er[hd+128]);
      }
      #pragma unroll
      for (int t = 0; t < 8; ++t){
        float4 av = *(const float4*)&sc[tg*8+t][s4*4];   // broadcast
        c0[t] += av.x*ea[0] + av.y*ea[1] + av.z*ea[2] + av.w*ea[3];
        c1[t] += av.x*eb[0] + av.y*eb[1] + av.z*eb[2] + av.w*eb[3];
      }
    }
    #pragma unroll
    for (int t = 0; t < 8; ++t){
      comb[tg*8+t][hd]     = c0[t];
      comb[tg*8+t][hd+128] = c1[t];
    }
  }
  for (int r = 0; r < 16; ++r) comb[r][256 + tid] = h_sm[r][tid];
  __syncthreads();
  // phase 4: attn_out = tanh(W_attn . comb + b)
  {
    int j2 = tid & 127, tg = tid >> 7;
    float4 a0[8], a1[8];
    #pragma unroll
    for (int t=0;t<8;++t){ a0[t]={0,0,0,0}; a1[t]={0,0,0,0}; }
    const uint4* W0 = (const uint4*)(Wattn + (size_t)j2*512);
    const uint4* W1 = (const uint4*)(Wattn + (size_t)(j2+128)*512);
    for (int oct = 0; oct < 64; ++oct){
      float4 w0lo, w0hi, w1lo, w1hi;
      unpack8(W0[oct], w0lo, w0hi);
      unpack8(W1[oct], w1lo, w1hi);
      #pragma unroll
      for (int t = 0; t < 8; ++t){
        const float4* cp = (const float4*)&comb[tg*8+t][oct*8]; // broadcast
        float4 clo = cp[0], chi = cp[1];
        a0[t] += w0lo*clo + w0hi*chi;
        a1[t] += w1lo*clo + w1hi*chi;
      }
    }
    float bi0 = battn[j2], bi1 = battn[j2+128];
    #pragma unroll
    for (int t = 0; t < 8; ++t){
      size_t row = (size_t)((b<<7) + t0 + tg*8 + t)*H_;
      attn_out[row + j2]     = f2bf(tanhf(hsum4(a0[t]) + bi0));
      attn_out[row + j2+128] = f2bf(tanhf(hsum4(a1[t]) + bi1));
    }
  }
}

// ---------------- vocab projection: [4096,256]bf16 @ W_out^T -> fp32 ----------
// SERPENTINE n-loop with store/compute overlap. 2000 blocks (16 mb x 125 ng),
// 512 thr / 8 waves. Each block: 256-row band, A held in REGISTERS (64 VGPR:
// 2 mi x 8 k0 short8 per lane), loops 4 n-steps of 64 cols. Per step: B panel
// (64x256 bf16 = 32 KB) in double-buffered LDS; stores of step s issued
// fire-and-forget and drain under step s+1's compute. Counted FIFO vmcnt
// (in-order, m135): arrival wait = exactly (32 stores + 4 stage) newer ops.
// Zero-cost asm(""::: "memory") fences pin stores->stage issue order so the
// counts hold. 2 barriers per n-step, amortized over 64 MFMA/wave.
#define VB_STAGE(bufi, s) do { \
    _Pragma("unroll") \
    for (int i_ = 0; i_ < 4; ++i_){ \
      int c_ = tid + i_*512; \
      int r_ = c_ >> 5; \
      int sc_ = (c_ & 31) ^ (r_ & 7); \
      GLOAD_LDS16(Wb + (size_t)(ncol0 + (s)*64 + r_)*256 + sc_*8, \
                  &Bsm[bufi][c_*8]); \
    } \
  } while(0)

#define VB_STEP(s, Wlit, DOSTAGE) do { \
    asm volatile("s_waitcnt vmcnt(" Wlit ")" ::: "memory"); \
    __builtin_amdgcn_s_barrier(); \
    floatx4 acc[2][4]; \
    _Pragma("unroll") \
    for (int mi=0;mi<2;++mi) \
      _Pragma("unroll") \
      for (int ni=0;ni<4;++ni) acc[mi][ni]=(floatx4){0.f,0.f,0.f,0.f}; \
    _Pragma("unroll") \
    for (int k0=0;k0<8;++k0){ \
      short8 bfr[4]; \
      _Pragma("unroll") \
      for (int ni=0;ni<4;++ni) \
        bfr[ni] = *(const short8*)&Bsm[(s)&1][(ni*16+llo)*256 + (((k0*4+lhi)^(llo&7))<<3)]; \
      _Pragma("unroll") \
      for (int ni=0;ni<4;++ni){ \
        acc[0][ni] = __builtin_amdgcn_mfma_f32_16x16x32_bf16(af[0][k0], bfr[ni], acc[0][ni], 0,0,0); \
        acc[1][ni] = __builtin_amdgcn_mfma_f32_16x16x32_bf16(af[1][k0], bfr[ni], acc[1][ni], 0,0,0); \
      } \
    } \
    asm volatile("s_waitcnt lgkmcnt(0)" ::: "memory"); \
    __builtin_amdgcn_s_barrier(); \
    _Pragma("unroll") \
    for (int ni=0;ni<4;++ni){ \
      int col_ = ncol0 + (s)*64 + ni*16 + llo; \
      _Pragma("unroll") \
      for (int mi=0;mi<2;++mi){ \
        _Pragma("unroll") \
        for (int r_=0;r_<4;++r_){ \
          int row_ = mrow0 + mi*16 + lhi*4 + r_; \
          out[(size_t)row_*V_ + col_] = acc[mi][ni][r_] + bpre[s][ni]; \
        } \
      } \
    } \
    asm volatile("" ::: "memory"); \
    if (DOSTAGE) VB_STAGE((s)&1, (s)+2); \
    asm volatile("" ::: "memory"); \
  } while(0)

__global__ __launch_bounds__(512) void k_vocab(
    const unsigned short* __restrict__ A,   // attn_out bf16 [4096][256]
    const unsigned short* __restrict__ Wb,  // W_out bf16 [V][256]
    const float* __restrict__ bout,         // [V]
    float* __restrict__ out)                // [4096][V]
{
  __shared__ alignas(16) unsigned short Bsm[2][64*256];  // 2 x 32 KB
  int bid = blockIdx.x;                 // 2000 blocks
  int xcd = bid & 7;
  int gid = xcd*250 + (bid >> 3);       // bijective chunked (2000 % 8 == 0)
  int mb = gid / 125, ng = gid % 125;   // consecutive gids: same mb, ng++
  int tid = threadIdx.x;
  int ln  = tid & 63;
  int w   = tid >> 6;                   // 8 waves, wave w: rows w*32..+31
  int llo = ln & 15, lhi = ln >> 4;
  int mrow0 = mb*256 + w*32;
  int ncol0 = ng*256;

  // A resident in registers: 2 mi x 8 k0 x short8 (64 VGPR/lane)
  short8 af[2][8];
  #pragma unroll
  for (int mi=0;mi<2;++mi)
    #pragma unroll
    for (int k0=0;k0<8;++k0)
      af[mi][k0] = *(const short8*)(A + (size_t)(mrow0 + mi*16 + llo)*256 + k0*32 + lhi*8);
  // biases for all 4 steps preloaded (keeps the loop's vmcnt queue clean)
  float bpre[4][4];
  #pragma unroll
  for (int s=0;s<4;++s)
    #pragma unroll
    for (int ni=0;ni<4;++ni)
      bpre[s][ni] = bout[ncol0 + s*64 + ni*16 + llo];

  VB_STAGE(0, 0);
  VB_STAGE(1, 1);

  // W accounting (FIFO): newer-than-stage(s) = stores(s-1)[32] + stage(s+1)[4]
  VB_STEP(0, "4",  1);   // newer = stage(1) only
  VB_STEP(1, "36", 1);   // stores(0) 32 + stage(2) 4
  VB_STEP(2, "36", 0);   // stores(1) 32 + stage(3) 4
  VB_STEP(3, "32", 0);   // stores(2) 32
}

extern "C" void kernel_launch(void* const* d_in, const int* in_sizes, int n_in,
                              void* d_out, int out_size, void* d_ws, size_t ws_size,
                              hipStream_t stream){
  const int*   indices_de = (const int*)d_in[0];
  const int*   lengths_de = (const int*)d_in[1];
  const int*   indices_en = (const int*)d_in[2];
  const float* emb_enc   = (const float*)d_in[4];
  const float* emb_dec   = (const float*)d_in[5];
  const float* W_ih_enc  = (const float*)d_in[6];
  const float* W_hh_enc  = (const float*)d_in[7];
  const float* b_ih_enc  = (const float*)d_in[8];
  const float* b_hh_enc  = (const float*)d_in[9];
  const float* W_ih_dec  = (const float*)d_in[10];
  const float* W_hh_dec  = (const float*)d_in[11];
  const float* b_ih_dec  = (const float*)d_in[12];
  const float* b_hh_dec  = (const float*)d_in[13];
  const float* W_attn    = (const float*)d_in[14];
  const float* b_attn    = (const float*)d_in[15];
  const float* W_out     = (const float*)d_in[16];
  const float* b_out     = (const float*)d_in[17];

  char* ws = (char*)d_ws;
  size_t o = 0;
  float* Xih_enc = (float*)(ws + o); o += (size_t)4096*256*4;
  float* Xih_dec = (float*)(ws + o); o += (size_t)4096*256*4;
  unsigned short* enc_bf = (unsigned short*)(ws + o); o += (size_t)4096*256*2;
  float* hdec    = (float*)(ws + o); o += (size_t)4096*256*4;
  unsigned short* attn_o  = (unsigned short*)(ws + o); o += (size_t)4096*256*2;
  unsigned short* Wout_bf = (unsigned short*)(ws + o); o += (size_t)V_*256*2;
  unsigned short* Wattn_bf= (unsigned short*)(ws + o); o += (size_t)256*512*2;

  k_prep<<<8640, 256, 0, stream>>>(
      W_out, Wout_bf, W_attn, Wattn_bf,
      indices_de, emb_enc, W_ih_enc, b_ih_enc, b_hh_enc, Xih_enc,
      indices_en, emb_dec, W_ih_dec, b_ih_dec, b_hh_dec, Xih_dec);
  k_rnn2<<<32, 512, 0, stream>>>(W_hh_enc, W_hh_dec, Xih_enc, Xih_dec,
                                 lengths_de, enc_bf, hdec);
  k_attn<<<256, 256, 0, stream>>>(enc_bf, hdec, lengths_de, Wattn_bf, b_attn, attn_o);
  k_vocab<<<2000, 512, 0, stream>>>(attn_o, Wout_bf, b_out, (float*)d_out);
}